// Round 5
// baseline (335.227 us; speedup 1.0000x reference)
//
#include <hip/hip_runtime.h>

typedef __bf16 bf16;
typedef __attribute__((ext_vector_type(8))) __bf16 bf16x8;
typedef __attribute__((ext_vector_type(2))) __bf16 bf16x2;
typedef __attribute__((ext_vector_type(4))) float f32x4;
typedef __attribute__((ext_vector_type(8))) unsigned short ushort8;   // 16B
typedef __attribute__((ext_vector_type(4))) unsigned short ushort4v;  // 8B
typedef __attribute__((ext_vector_type(4))) short short4v;            // 4 bf16 as shorts

__device__ __forceinline__ unsigned short f2bf(float f) {
    union { float f; unsigned int u; } v; v.f = f;
    unsigned int u = v.u;
    return (unsigned short)((u + 0x7fffu + ((u >> 16) & 1u)) >> 16);
}

#if __has_builtin(__builtin_amdgcn_cvt_pk_bf16_f32)
__device__ __forceinline__ unsigned int pk2bf(float a, float b) {
    union { bf16x2 v; unsigned int u; } c;
    c.v = __builtin_amdgcn_cvt_pk_bf16_f32(a, b);
    return c.u;
}
#else
__device__ __forceinline__ unsigned int pk2bf(float a, float b) {
    return (unsigned int)f2bf(a) | ((unsigned int)f2bf(b) << 16);
}
#endif

__device__ __forceinline__ f32x4 mfma16(bf16x8 a, bf16x8 b, f32x4 c) {
    return __builtin_amdgcn_mfma_f32_16x16x32_bf16(a, b, c, 0, 0, 0);
}

// 16x16x16 bf16 MFMA (K=16): A/B are 4 bf16 per lane. C/D layout same as K=32 version.
__device__ __forceinline__ f32x4 mfma_pv(short4v a, short4v b, f32x4 c) {
#if __has_builtin(__builtin_amdgcn_mfma_f32_16x16x16bf16_1k)
    return __builtin_amdgcn_mfma_f32_16x16x16bf16_1k(a, b, c, 0, 0, 0);
#else
    f32x4 d;
    asm("v_mfma_f32_16x16x16_bf16 %0, %1, %2, %3" : "=v"(d) : "v"(a), "v"(b), "v"(c));
    return d;
#endif
}

// ---------------- fused fp32 -> bf16 convert ----------------
__global__ void cvt3_f32_bf16(const float* __restrict__ x, const float* __restrict__ wq,
                              const float* __restrict__ wp,
                              unsigned short* __restrict__ xb, unsigned short* __restrict__ wqb,
                              unsigned short* __restrict__ wpb) {
    int i = blockIdx.x * 256 + threadIdx.x;   // float4 index
    const float* in; unsigned short* out; int base;
    if (i < 1572864)      { in = x;  out = xb;  base = i; }
    else if (i < 2015232) { in = wq; out = wqb; base = i - 1572864; }
    else if (i < 2162688) { in = wp; out = wpb; base = i - 2015232; }
    else return;
    float4 f = reinterpret_cast<const float4*>(in)[base];
    union { ushort4v v; unsigned int u[2]; } o;
    o.u[0] = pk2bf(f.x, f.y);
    o.u[1] = pk2bf(f.z, f.w);
    reinterpret_cast<ushort4v*>(out)[base] = o.v;
}

// ---------------- QKV GEMM: [8192x768] x [2304x768]^T, scatter to Q,K,Vt ----------------
// Q pre-scaled by SCALE*log2(e). V^T stored with keys permuted within 32-groups:
// newpos = quad*8 + km*4 + r  (quad=(k>>2)&3, km=(k>>4)&1, r=k&3) so one b128 LDS read
// in attention yields both K=16 PV B-fragments.
__global__ __launch_bounds__(256) void qkv_gemm(const unsigned short* __restrict__ A,
                                                const unsigned short* __restrict__ W,
                                                unsigned short* __restrict__ Qg,
                                                unsigned short* __restrict__ Kg,
                                                unsigned short* __restrict__ Vtg) {
    __shared__ __align__(16) unsigned short As[128 * 40];
    __shared__ __align__(16) unsigned short Bs[128 * 40];
    const int t = threadIdx.x;
    const int w = t >> 6, l = t & 63;
    const int wm = (w >> 1) * 64, wn = (w & 1) * 64;
    const int lr = l & 15, lq = l >> 4;
    const int m0 = blockIdx.y * 128, n0 = blockIdx.x * 128;
    f32x4 acc[4][4] = {};
    for (int k0 = 0; k0 < 768; k0 += 32) {
        __syncthreads();
#pragma unroll
        for (int i = 0; i < 2; ++i) {
            int v = t + i * 256;
            int r = v >> 2, c8 = (v & 3) * 8;
            *reinterpret_cast<ushort8*>(&As[r * 40 + c8]) =
                *reinterpret_cast<const ushort8*>(&A[(m0 + r) * 768 + k0 + c8]);
            *reinterpret_cast<ushort8*>(&Bs[r * 40 + c8]) =
                *reinterpret_cast<const ushort8*>(&W[(n0 + r) * 768 + k0 + c8]);
        }
        __syncthreads();
        bf16x8 af[4], bfr[4];
#pragma unroll
        for (int mt = 0; mt < 4; ++mt)
            af[mt] = *reinterpret_cast<const bf16x8*>(&As[(wm + mt * 16 + lr) * 40 + lq * 8]);
#pragma unroll
        for (int nt = 0; nt < 4; ++nt)
            bfr[nt] = *reinterpret_cast<const bf16x8*>(&Bs[(wn + nt * 16 + lr) * 40 + lq * 8]);
#pragma unroll
        for (int mt = 0; mt < 4; ++mt)
#pragma unroll
            for (int nt = 0; nt < 4; ++nt)
                acc[mt][nt] = mfma16(af[mt], bfr[nt], acc[mt][nt]);
    }
#pragma unroll
    for (int nt = 0; nt < 4; ++nt) {
        int gn = n0 + wn + nt * 16 + lr;
        int tsel = gn / 768, rem = gn - tsel * 768;
        int h = rem / 96, d = rem - h * 96;
#pragma unroll
        for (int mt = 0; mt < 4; ++mt) {
#pragma unroll
            for (int r = 0; r < 4; ++r) {
                int gm = m0 + wm + mt * 16 + lq * 4 + r;
                int b = gm >> 12, n = gm & 4095;
                int bh = b * 8 + h;
                float val = acc[mt][nt][r];
                if (tsel == 0)      Qg[(bh * 4096 + n) * 96 + d] = f2bf(val * 0.14724444f);
                else if (tsel == 1) Kg[(bh * 4096 + n) * 96 + d] = f2bf(val);
                else {
                    int k5 = n & 31;
                    int np = (n & ~31) | (((k5 >> 2) & 3) * 8 + ((k5 >> 4) & 1) * 4 + (k5 & 3));
                    Vtg[(bh * 96 + d) * 4096 + np] = f2bf(val);
                }
            }
        }
    }
}

// ---------------- Flash attention: P-in-registers, K=16 PV MFMAs ----------------
// 512 threads = 8 waves: wr=w>>1 (row group of 32), wk=w&1 (key group of 32). Br=128, Tc=64.
// S^T C-layout == A-operand layout of 16x16x16 MFMA -> no P LDS round-trip, no mid barrier.
// l (row-sum) via ones-B K=16 MFMA. Cross-wave wk reduce in epilogue (linear softmax).
__global__ __launch_bounds__(512, 4) void attn_kernel(const unsigned short* __restrict__ Qg,
                                                      const unsigned short* __restrict__ Kg,
                                                      const unsigned short* __restrict__ Vtg,
                                                      unsigned short* __restrict__ Og) {
    __shared__ __align__(16) char lds[36864];               // sized by epilogue red buffer
    unsigned short* Qs = (unsigned short*)lds;              // 128 x 96   (prologue only)
    unsigned short* Ks = (unsigned short*)lds;              // 64 x 104   (aliases Qs)
    unsigned short* Vs = (unsigned short*)(lds + 13312);    // 96 x 72    (perm keys)
    float*          red = (float*)lds;                      // epilogue reduce buffer

    const int t = threadIdx.x;
    const int w = t >> 6, l = t & 63;
    const int wr = w >> 1, wk = w & 1;
    const int lr = l & 15, lq = l >> 4;
    const int bh = blockIdx.y;
    const int q0 = blockIdx.x * 128;
    const int qbase = bh * 4096 * 96;

    // stage Q tile
#pragma unroll
    for (int i = 0; i < 3; ++i) {
        int v = t + i * 512;
        int r = v / 12, c8 = (v % 12) * 8;
        *reinterpret_cast<ushort8*>(&Qs[r * 96 + c8]) =
            *reinterpret_cast<const ushort8*>(&Qg[qbase + (q0 + r) * 96 + c8]);
    }
    __syncthreads();
    // hoist Q fragments (B-operand of S^T)
    bf16x8 aq[2][3];
#pragma unroll
    for (int qn = 0; qn < 2; ++qn)
#pragma unroll
        for (int kq = 0; kq < 3; ++kq)
            aq[qn][kq] = *reinterpret_cast<const bf16x8*>(&Qs[(wr * 32 + qn * 16 + lr) * 96 + kq * 32 + lq * 8]);

    short4v ones16;
#pragma unroll
    for (int i = 0; i < 4; ++i) ones16[i] = (short)0x3F80;  // bf16 1.0

    f32x4 acc[2][6] = {};   // [qn][dn]
    f32x4 acc_l[2] = {};

    for (int kv0 = 0; kv0 < 4096; kv0 += 64) {
        __syncthreads();
        // stage K (64x96) and Vt (96x64, keys pre-permuted in memory)
#pragma unroll
        for (int j = 0; j < 3; ++j) {
            int v = t + j * 512;
            if (v < 768) {
                int r = v / 12, c8 = (v % 12) * 8;
                *reinterpret_cast<ushort8*>(&Ks[r * 104 + c8]) =
                    *reinterpret_cast<const ushort8*>(&Kg[qbase + (kv0 + r) * 96 + c8]);
            } else {
                int u = v - 768;
                int d = u >> 3, c8v = (u & 7) * 8;
                *reinterpret_cast<ushort8*>(&Vs[d * 72 + c8v]) =
                    *reinterpret_cast<const ushort8*>(&Vtg[(bh * 96 + d) * 4096 + kv0 + c8v]);
            }
        }
        __syncthreads();
        // S^T = K Q^T: s[km][qn], rows = keys (wk*32+km*16+quad*4+r), cols = qrows
        f32x4 s[2][2] = {};
#pragma unroll
        for (int kq = 0; kq < 3; ++kq) {
            bf16x8 bk[2];
#pragma unroll
            for (int km = 0; km < 2; ++km)
                bk[km] = *reinterpret_cast<const bf16x8*>(&Ks[(wk * 32 + km * 16 + lr) * 104 + kq * 32 + lq * 8]);
#pragma unroll
            for (int qn = 0; qn < 2; ++qn)
#pragma unroll
                for (int km = 0; km < 2; ++km)
                    s[km][qn] = mfma16(bk[km], aq[qn][kq], s[km][qn]);
        }
        // p = exp2(s) packed to bf16: C-layout == 16x16x16 A-layout (m=qrow, k=key)
        union PF { unsigned int u[2]; short4v s4; } p[2][2];
#pragma unroll
        for (int km = 0; km < 2; ++km)
#pragma unroll
            for (int qn = 0; qn < 2; ++qn) {
                p[km][qn].u[0] = pk2bf(__builtin_amdgcn_exp2f(s[km][qn][0]),
                                       __builtin_amdgcn_exp2f(s[km][qn][1]));
                p[km][qn].u[1] = pk2bf(__builtin_amdgcn_exp2f(s[km][qn][2]),
                                       __builtin_amdgcn_exp2f(s[km][qn][3]));
            }
        // O += P V: one b128 per dn holds both km B-frags (permuted V layout)
#pragma unroll
        for (int dn = 0; dn < 6; ++dn) {
            union { bf16x8 v8; short4v s4[2]; } vv;
            vv.v8 = *reinterpret_cast<const bf16x8*>(&Vs[(dn * 16 + lr) * 72 + wk * 32 + lq * 8]);
#pragma unroll
            for (int qn = 0; qn < 2; ++qn)
#pragma unroll
                for (int km = 0; km < 2; ++km)
                    acc[qn][dn] = mfma_pv(p[km][qn].s4, vv.s4[km], acc[qn][dn]);
        }
#pragma unroll
        for (int qn = 0; qn < 2; ++qn)
#pragma unroll
            for (int km = 0; km < 2; ++km)
                acc_l[qn] = mfma_pv(p[km][qn].s4, ones16, acc_l[qn]);
    }

    // ---- cross-wave reduce over wk pairs (two passes, fp32, stride 36 floats) ----
    const int base = (wr * 64 + l) * 36;
    __syncthreads();
    if (wk == 1) {
#pragma unroll
        for (int qn = 0; qn < 2; ++qn) {
#pragma unroll
            for (int dn = 0; dn < 3; ++dn)
                *reinterpret_cast<f32x4*>(&red[base + (qn * 3 + dn) * 4]) = acc[qn][dn];
            *reinterpret_cast<f32x4*>(&red[base + 24 + qn * 4]) = acc_l[qn];
        }
    }
    __syncthreads();
    if (wk == 0) {
#pragma unroll
        for (int qn = 0; qn < 2; ++qn) {
#pragma unroll
            for (int dn = 0; dn < 3; ++dn)
                acc[qn][dn] += *reinterpret_cast<const f32x4*>(&red[base + (qn * 3 + dn) * 4]);
            acc_l[qn] += *reinterpret_cast<const f32x4*>(&red[base + 24 + qn * 4]);
        }
    }
    __syncthreads();
    if (wk == 1) {
#pragma unroll
        for (int qn = 0; qn < 2; ++qn)
#pragma unroll
            for (int dn = 3; dn < 6; ++dn)
                *reinterpret_cast<f32x4*>(&red[base + (qn * 3 + dn - 3) * 4]) = acc[qn][dn];
    }
    __syncthreads();
    if (wk == 0) {
#pragma unroll
        for (int qn = 0; qn < 2; ++qn)
#pragma unroll
            for (int dn = 3; dn < 6; ++dn)
                acc[qn][dn] += *reinterpret_cast<const f32x4*>(&red[base + (qn * 3 + dn - 3) * 4]);
        // normalize + write attn_out[b][n][h*96+d] (bf16 scratch)
        const int b = bh >> 3, h = bh & 7;
#pragma unroll
        for (int qn = 0; qn < 2; ++qn) {
#pragma unroll
            for (int r = 0; r < 4; ++r) {
                float inv = 1.f / acc_l[qn][r];
                int n = q0 + wr * 32 + qn * 16 + lq * 4 + r;
                int rowoff = (b * 4096 + n) * 768 + h * 96;
#pragma unroll
                for (int dn = 0; dn < 6; ++dn)
                    Og[rowoff + dn * 16 + lr] = f2bf(acc[qn][dn][r] * inv);
            }
        }
    }
}

// ---------------- proj GEMM: [8192x768] x [768x768]^T -> FP32 out ----------------
__global__ __launch_bounds__(256) void proj_gemm(const unsigned short* __restrict__ A,
                                                 const unsigned short* __restrict__ W,
                                                 float* __restrict__ out) {
    __shared__ __align__(16) unsigned short As[128 * 40];
    __shared__ __align__(16) unsigned short Bs[128 * 40];
    const int t = threadIdx.x;
    const int w = t >> 6, l = t & 63;
    const int wm = (w >> 1) * 64, wn = (w & 1) * 64;
    const int lr = l & 15, lq = l >> 4;
    const int m0 = blockIdx.y * 128, n0 = blockIdx.x * 128;
    f32x4 acc[4][4] = {};
    for (int k0 = 0; k0 < 768; k0 += 32) {
        __syncthreads();
#pragma unroll
        for (int i = 0; i < 2; ++i) {
            int v = t + i * 256;
            int r = v >> 2, c8 = (v & 3) * 8;
            *reinterpret_cast<ushort8*>(&As[r * 40 + c8]) =
                *reinterpret_cast<const ushort8*>(&A[(m0 + r) * 768 + k0 + c8]);
            *reinterpret_cast<ushort8*>(&Bs[r * 40 + c8]) =
                *reinterpret_cast<const ushort8*>(&W[(n0 + r) * 768 + k0 + c8]);
        }
        __syncthreads();
        bf16x8 af[4], bfr[4];
#pragma unroll
        for (int mt = 0; mt < 4; ++mt)
            af[mt] = *reinterpret_cast<const bf16x8*>(&As[(wm + mt * 16 + lr) * 40 + lq * 8]);
#pragma unroll
        for (int nt = 0; nt < 4; ++nt)
            bfr[nt] = *reinterpret_cast<const bf16x8*>(&Bs[(wn + nt * 16 + lr) * 40 + lq * 8]);
#pragma unroll
        for (int mt = 0; mt < 4; ++mt)
#pragma unroll
            for (int nt = 0; nt < 4; ++nt)
                acc[mt][nt] = mfma16(af[mt], bfr[nt], acc[mt][nt]);
    }
#pragma unroll
    for (int nt = 0; nt < 4; ++nt) {
        int gn = n0 + wn + nt * 16 + lr;
#pragma unroll
        for (int mt = 0; mt < 4; ++mt) {
#pragma unroll
            for (int r = 0; r < 4; ++r) {
                int gm = m0 + wm + mt * 16 + lq * 4 + r;
                out[gm * 768 + gn] = acc[mt][nt][r];
            }
        }
    }
}

extern "C" void kernel_launch(void* const* d_in, const int* in_sizes, int n_in,
                              void* d_out, int out_size, void* d_ws, size_t ws_size,
                              hipStream_t stream) {
    const float* x     = (const float*)d_in[0];   // [2,4096,768] fp32
    const float* wqkv  = (const float*)d_in[1];   // [2304,768] fp32
    const float* wproj = (const float*)d_in[2];   // [768,768] fp32
    float* out = (float*)d_out;                   // fp32 [2,4096,768]
    char* ws = (char*)d_ws;
    unsigned short* xb     = (unsigned short*)(ws);             // 12582912
    unsigned short* wqkvb  = (unsigned short*)(ws + 12582912);  // 3538944
    unsigned short* wprojb = (unsigned short*)(ws + 16121856);  // 1179648
    unsigned short* Qg     = (unsigned short*)(ws + 17301504);  // [B,H,N,D]
    unsigned short* Kg     = (unsigned short*)(ws + 29884416);  // [B,H,N,D]
    unsigned short* Vtg    = (unsigned short*)(ws + 42467328);  // [B,H,D,N] (perm keys)
    unsigned short* attnb  = xb;                                // reuse: [B,N,C] bf16

    cvt3_f32_bf16<<<8448, 256, 0, stream>>>(x, wqkv, wproj, xb, wqkvb, wprojb);
    qkv_gemm<<<dim3(18, 64), 256, 0, stream>>>(xb, wqkvb, Qg, Kg, Vtg);
    attn_kernel<<<dim3(32, 16), 512, 0, stream>>>(Qg, Kg, Vtg, attnb);
    proj_gemm<<<dim3(6, 64), 256, 0, stream>>>(attnb, wprojb, out);
}